// Round 9
// baseline (105.152 us; speedup 1.0000x reference)
//
#include <hip/hip_runtime.h>

#define ENT_GRID 16
#define ENT_DIM  64
#define EMB      1024   // ENT_GRID * ENT_DIM
#define LN_EPS   1e-5f

// ---------- grouping machinery (device-side, capture-safe) ----------

__global__ void hist_kernel(const int* __restrict__ ids, int* __restrict__ hist, int B) {
    int i = blockIdx.x * blockDim.x + threadIdx.x;
    if (i < B) atomicAdd(&hist[ids[i]], 1);
}

__global__ __launch_bounds__(1024)
void scan_kernel(const int* __restrict__ hist, int* __restrict__ cursor, int n) {
    const int t = threadIdx.x;
    const int ITEMS = (n + 1023) / 1024;
    int vals[8];
    int lsum = 0;
#pragma unroll
    for (int k = 0; k < 8; ++k) {
        int i = t * ITEMS + k;
        int v = (k < ITEMS && i < n) ? hist[i] : 0;
        vals[k] = v;
        lsum += v;
    }
    __shared__ int s[1024];
    s[t] = lsum;
    __syncthreads();
    for (int off = 1; off < 1024; off <<= 1) {
        int v = (t >= off) ? s[t - off] : 0;
        __syncthreads();
        s[t] += v;
        __syncthreads();
    }
    int run = s[t] - lsum;
#pragma unroll
    for (int k = 0; k < 8; ++k) {
        int i = t * ITEMS + k;
        if (k < ITEMS && i < n) cursor[i] = run;
        run += vals[k];
    }
}

__global__ void scatter_kernel(const int* __restrict__ ids, int* __restrict__ cursor,
                               int* __restrict__ perm, int B) {
    int i = blockIdx.x * blockDim.x + threadIdx.x;
    if (i < B) {
        int pos = atomicAdd(&cursor[ids[i]], 1);
        perm[pos] = i;
    }
    // after: cursor[r] == END offset of group r; start = cursor[r] - hist[r]
}

__device__ __forceinline__ float dot4(float4 a, float4 b) {
    return a.x * b.x + a.y * b.y + a.z * b.z + a.w * b.w;
}

// ---------- kernel A: wave-autonomous projection ----------
// One WAVE per job (r, q), q in [0,16). Lane l owns output i = 64q + l:
// tran row i (64 B, lanes contiguous -> wave reads 4 KiB contiguous) in 16
// VGPR. Per batch row of group r: e-block d=i>>4 (16 lanes share one 64 B
// line, L1 broadcast), dot, wave64 shfl partial {sum,sumsq} -> part[b*16+q],
// scalar x store (256 B/wave). NO LDS, NO barriers, no cross-wave coupling.
__global__ __launch_bounds__(256, 7)
void wproj_wavejob_kernel(const float* __restrict__ ent_emb,
                          const float* __restrict__ rel_tran,
                          const float* __restrict__ rel_bias,
                          const int*   __restrict__ hist,
                          const int*   __restrict__ cursor_end,
                          const int*   __restrict__ perm,
                          float* __restrict__ xout,
                          float2* __restrict__ part,
                          int njob) {
    const int job = (blockIdx.x * blockDim.x + threadIdx.x) >> 6;
    if (job >= njob) return;
    const int r = job >> 4;
    const int q = job & 15;

    const int cnt = hist[r];
    if (cnt == 0) return;
    const int start = cursor_end[r] - cnt;

    const int lane = threadIdx.x & 63;
    const int i = q * 64 + lane;        // output index in [0,1024)
    const int d = i >> 4;               // e-block index

    // this lane's tran row (64 B); wave covers rows 64q..64q+63 contiguous
    const float4* __restrict__ tr4 = reinterpret_cast<const float4*>(
        rel_tran + (size_t)r * (ENT_DIM * ENT_GRID * ENT_GRID) + (size_t)i * ENT_GRID);
    const float4 a0 = tr4[0], a1 = tr4[1], a2 = tr4[2], a3 = tr4[3];
    const float bv = rel_bias[(size_t)r * EMB + i];

    const int last = start + cnt - 1;
    int b = perm[start];
    for (int j = 0; j < cnt; ++j) {
        const int bnext = perm[min(start + j + 1, last)];   // depth-1 prefetch

        const float4* __restrict__ e4 =
            reinterpret_cast<const float4*>(ent_emb + (size_t)b * EMB + d * ENT_GRID);
        const float4 e0 = e4[0], e1 = e4[1], e2 = e4[2], e3 = e4[3];

        const float x = bv + dot4(a0, e0) + dot4(a1, e1) + dot4(a2, e2) + dot4(a3, e3);
        xout[(size_t)b * EMB + i] = x;              // fire & forget

        float s = x, ss = x * x;
#pragma unroll
        for (int off = 32; off > 0; off >>= 1) {
            s  += __shfl_xor(s, off, 64);
            ss += __shfl_xor(ss, off, 64);
        }
        if (lane == 0) part[(size_t)b * 16 + q] = make_float2(s, ss);

        b = bnext;
    }
}

// ---------- kernel B: in-place LayerNorm over out rows ----------
__global__ __launch_bounds__(256, 8)
void ln_kernel(const float2* __restrict__ part,
               const float*  __restrict__ ln_w,
               const float*  __restrict__ ln_b,
               float* __restrict__ out) {
    const int b = blockIdx.x;
    const int t = threadIdx.x;
    __shared__ float sstat[2];

    if (t < 64) {
        float s = 0.0f, ss = 0.0f;
        if (t < 16) { const float2 p = part[(size_t)b * 16 + t]; s = p.x; ss = p.y; }
#pragma unroll
        for (int off = 8; off > 0; off >>= 1) {
            s  += __shfl_xor(s, off, 64);
            ss += __shfl_xor(ss, off, 64);
        }
        if (t == 0) {
            const float mu  = s * (1.0f / (float)EMB);
            const float var = ss * (1.0f / (float)EMB) - mu * mu;
            sstat[0] = mu;
            sstat[1] = rsqrtf(var + LN_EPS);
        }
    }
    __syncthreads();
    const float mu = sstat[0], rstd = sstat[1];

    float4* __restrict__ o4 = reinterpret_cast<float4*>(out + (size_t)b * EMB);
    const float4 x  = o4[t];
    const float4 w  = reinterpret_cast<const float4*>(ln_w)[t];
    const float4 bb = reinterpret_cast<const float4*>(ln_b)[t];
    float4 o;
    o.x = (x.x - mu) * rstd * w.x + bb.x;
    o.y = (x.y - mu) * rstd * w.y + bb.y;
    o.z = (x.z - mu) * rstd * w.z + bb.z;
    o.w = (x.w - mu) * rstd * w.w + bb.w;
    o4[t] = o;
}

extern "C" void kernel_launch(void* const* d_in, const int* in_sizes, int n_in,
                              void* d_out, int out_size, void* d_ws, size_t ws_size,
                              hipStream_t stream) {
    const float* ent_emb  = (const float*)d_in[0];
    const int*   proj_ids = (const int*)  d_in[1];
    const float* rel_tran = (const float*)d_in[2];
    const float* rel_bias = (const float*)d_in[3];
    const float* ln_w     = (const float*)d_in[4];
    const float* ln_b     = (const float*)d_in[5];
    float* out = (float*)d_out;

    const int B  = in_sizes[1];                                     // 8192
    const int NR = in_sizes[2] / (ENT_DIM * ENT_GRID * ENT_GRID);   // 5000

    // ws layout: [hist NR][cursor NR][perm B][pad16][part float2 B*16]
    int* ws     = (int*)d_ws;
    int* hist   = ws;                    // [NR]
    int* cursor = ws + NR;               // [NR]
    int* perm   = ws + 2 * NR;           // [B]
    size_t off = (size_t)(2 * NR + B) * sizeof(int);
    off = (off + 15) & ~(size_t)15;
    float2* part = (float2*)((char*)d_ws + off);   // [B*16]

    hipMemsetAsync(hist, 0, (size_t)NR * sizeof(int), stream);
    hist_kernel<<<(B + 255) / 256, 256, 0, stream>>>(proj_ids, hist, B);
    scan_kernel<<<1, 1024, 0, stream>>>(hist, cursor, NR);
    scatter_kernel<<<(B + 255) / 256, 256, 0, stream>>>(proj_ids, cursor, perm, B);

    const int njob = NR * 16;                        // one wave per (r, q)
    const int blocksA = (njob * 64 + 255) / 256;     // 4 wave-jobs per block
    wproj_wavejob_kernel<<<blocksA, 256, 0, stream>>>(ent_emb, rel_tran, rel_bias,
                                                      hist, cursor, perm, out, part, njob);
    ln_kernel<<<B, 256, 0, stream>>>(part, ln_w, ln_b, out);
}

// Round 10
// 91.737 us; speedup vs baseline: 1.1462x; 1.1462x over previous
//
#include <hip/hip_runtime.h>

#define ENT_GRID 16
#define ENT_DIM  64
#define EMB      1024   // ENT_GRID * ENT_DIM
#define LN_EPS   1e-5f

// One block per batch row. 256 threads; each thread produces 4 of the 1024
// outputs. Embedding row staged in LDS (broadcast reads). Fused LayerNorm.
// Duplicate relation rows are served by the 256 MiB L3 (measured: explicit
// dedup structures never beat this — delivery rate, not bytes, is binding).
__global__ __launch_bounds__(256, 4)
void wproj_ln_kernel(const float* __restrict__ ent_emb,
                     const int*   __restrict__ proj_ids,
                     const float* __restrict__ rel_tran,
                     const float* __restrict__ rel_bias,
                     const float* __restrict__ ln_w,
                     const float* __restrict__ ln_b,
                     float* __restrict__ out) {
    const int b = blockIdx.x;
    const int t = threadIdx.x;

    const long long r = (long long)proj_ids[b];
    const float* __restrict__ tran = rel_tran + (size_t)r * (ENT_DIM * ENT_GRID * ENT_GRID); // 16384 f
    const float* __restrict__ bias = rel_bias + (size_t)r * (ENT_DIM * ENT_GRID);            // 1024 f
    const float* __restrict__ e    = ent_emb  + (size_t)b * EMB;

    __shared__ float se[EMB];          // 4 KiB embedding row
    __shared__ float wsum[4], wsq[4];  // per-wave partials

    // Stage embedding row: 256 threads x float4 = 1024 floats, fully coalesced.
    reinterpret_cast<float4*>(se)[t] = reinterpret_cast<const float4*>(e)[t];
    __syncthreads();

    float x[4];
    float sum = 0.0f, sumsq = 0.0f;

#pragma unroll
    for (int k = 0; k < 4; ++k) {
        const int i = t + k * 256;     // output index in [0,1024)
        const int d = i >> 4;          // ent_dim slot
        // each thread reads its 16-float tran row contiguously (64 B)
        const float4* __restrict__ tr = reinterpret_cast<const float4*>(tran + (size_t)i * ENT_GRID);
        const float4* __restrict__ er = reinterpret_cast<const float4*>(se + d * ENT_GRID);
        float acc = bias[i];
#pragma unroll
        for (int q = 0; q < 4; ++q) {
            float4 a  = tr[q];
            float4 ev = er[q];         // broadcast within 16-lane groups, no bank conflict
            acc += a.x * ev.x + a.y * ev.y + a.z * ev.z + a.w * ev.w;
        }
        x[k]  = acc;
        sum   += acc;
        sumsq += acc * acc;
    }

    // wave64 butterfly reduce
#pragma unroll
    for (int off = 32; off > 0; off >>= 1) {
        sum   += __shfl_xor(sum, off, 64);
        sumsq += __shfl_xor(sumsq, off, 64);
    }
    const int wid = t >> 6;
    if ((t & 63) == 0) { wsum[wid] = sum; wsq[wid] = sumsq; }
    __syncthreads();

    const float tsum = wsum[0] + wsum[1] + wsum[2] + wsum[3];
    const float tsq  = wsq[0]  + wsq[1]  + wsq[2]  + wsq[3];
    const float mu   = tsum * (1.0f / (float)EMB);
    const float var  = tsq * (1.0f / (float)EMB) - mu * mu;
    const float rstd = rsqrtf(var + LN_EPS);

    float* __restrict__ ob = out + (size_t)b * EMB;
#pragma unroll
    for (int k = 0; k < 4; ++k) {
        const int i = t + k * 256;
        ob[i] = (x[k] - mu) * rstd * ln_w[i] + ln_b[i];
    }
}

extern "C" void kernel_launch(void* const* d_in, const int* in_sizes, int n_in,
                              void* d_out, int out_size, void* d_ws, size_t ws_size,
                              hipStream_t stream) {
    const float* ent_emb  = (const float*)d_in[0];
    const int*   proj_ids = (const int*)  d_in[1];
    const float* rel_tran = (const float*)d_in[2];
    const float* rel_bias = (const float*)d_in[3];
    const float* ln_w     = (const float*)d_in[4];
    const float* ln_b     = (const float*)d_in[5];
    float* out = (float*)d_out;

    const int B = in_sizes[1];  // 8192 batch rows (one proj_id each)

    wproj_ln_kernel<<<B, 256, 0, stream>>>(ent_emb, proj_ids, rel_tran, rel_bias,
                                           ln_w, ln_b, out);
}